// Round 6
// baseline (83.018 us; speedup 1.0000x reference)
//
#include <hip/hip_runtime.h>

#define B_ROWS 32768
#define C_COLS 1000
#define NF4 250                 // C_COLS / 4
#define MAIN_BLOCKS 2048
#define WAVES_TOTAL (MAIN_BLOCKS * 4)
#define HIST_BLOCKS 16
#define BINS_PER_BLOCK 64       // 16 * 64 = 1024 >= 1000

// --- histogram: each of 16 blocks reads ALL labels into a full LDS
//     histogram, then writes only its owned 64-bin slice. No global
//     atomics, no zeroing required. Block 0 zeroes the ticket counter. ---
__global__ __launch_bounds__(256) void bsl_hist(const int* __restrict__ target,
                                                float* __restrict__ freq,
                                                unsigned int* __restrict__ counter) {
    __shared__ unsigned int lh[1024];
    const int tid = threadIdx.x;
    #pragma unroll
    for (int i = tid; i < 1024; i += 256) lh[i] = 0u;
    __syncthreads();
    const int4* t4 = reinterpret_cast<const int4*>(target);
    #pragma unroll 8
    for (int k = 0; k < 32; ++k) {
        int4 v = t4[tid + k * 256];
        atomicAdd(&lh[v.x], 1u);
        atomicAdd(&lh[v.y], 1u);
        atomicAdd(&lh[v.z], 1u);
        atomicAdd(&lh[v.w], 1u);
    }
    __syncthreads();
    const int bin = blockIdx.x * BINS_PER_BLOCK + tid;
    if (tid < BINS_PER_BLOCK && bin < C_COLS) freq[bin] = (float)lh[bin];
    if (blockIdx.x == 0 && tid == 0) *counter = 0u;
}

// --- main: round-2 proven body + last-block finalize (atomic ticket) ---
__global__ __launch_bounds__(256) void bsl_main(const float* __restrict__ pred,
                                                const int* __restrict__ target,
                                                const float* __restrict__ freq,
                                                float* __restrict__ partials,
                                                unsigned int* __restrict__ counter,
                                                float* __restrict__ out) {
    __shared__ float sfreq[C_COLS];
    __shared__ float swave[4];
    __shared__ bool winner;
    const int tid = threadIdx.x;
    const int lane = tid & 63;
    const int wib = tid >> 6;

    for (int i = tid; i < C_COLS; i += 256) sfreq[i] = freq[i];
    __syncthreads();
    const float4* sf4 = reinterpret_cast<const float4*>(sfreq);

    const int gwid = blockIdx.x * 4 + wib;
    float local = 0.0f;

    for (int row = gwid; row < B_ROWS; row += WAVES_TOTAL) {
        const int t = target[row];
        const float4* prow = reinterpret_cast<const float4*>(pred + (size_t)row * C_COLS);
        const int t4i = t >> 2, tm = t & 3;
        float partial = 0.0f, pt = 0.0f;
        #pragma unroll
        for (int k = 0; k < 4; ++k) {
            const int j = k * 64 + lane;
            if (j < NF4) {
                const float4 v = prow[j];
                const float4 f = sf4[j];
                partial += __expf(v.x) * f.x + __expf(v.y) * f.y
                         + __expf(v.z) * f.z + __expf(v.w) * f.w;
                if (j == t4i)
                    pt = (tm & 1) ? ((tm & 2) ? v.w : v.y)
                                  : ((tm & 2) ? v.z : v.x);
            }
        }
        #pragma unroll
        for (int off = 32; off > 0; off >>= 1)
            partial += __shfl_xor(partial, off, 64);
        const float ptb = __shfl(pt, t4i & 63, 64);
        local += logf(partial) - ptb - logf(sfreq[t]);
    }

    if (lane == 0) swave[wib] = local;
    __syncthreads();
    if (tid == 0) {
        partials[blockIdx.x] = swave[0] + swave[1] + swave[2] + swave[3];
        __threadfence();   // make partial visible device-wide before the ticket
        unsigned int t = atomicAdd(counter, 1u);
        winner = (t == MAIN_BLOCKS - 1);
    }
    __syncthreads();

    if (winner) {
        __threadfence();   // acquire: all partials visible
        float s = 0.0f;
        for (int i = tid; i < MAIN_BLOCKS; i += 256) s += partials[i];
        #pragma unroll
        for (int off = 32; off > 0; off >>= 1) s += __shfl_xor(s, off, 64);
        if (lane == 0) swave[wib] = s;
        __syncthreads();
        if (tid == 0)
            out[0] = (swave[0] + swave[1] + swave[2] + swave[3]) / (float)B_ROWS;
    }
}

extern "C" void kernel_launch(void* const* d_in, const int* in_sizes, int n_in,
                              void* d_out, int out_size, void* d_ws, size_t ws_size,
                              hipStream_t stream) {
    const float* pred = (const float*)d_in[0];
    const int* target = (const int*)d_in[1];

    float* freq            = (float*)d_ws;         // [1024]
    float* partials        = freq + 1024;          // [MAIN_BLOCKS]
    unsigned int* counter  = (unsigned int*)(partials + MAIN_BLOCKS);  // [1]

    bsl_hist<<<HIST_BLOCKS, 256, 0, stream>>>(target, freq, counter);
    bsl_main<<<MAIN_BLOCKS, 256, 0, stream>>>(pred, target, freq, partials,
                                              counter, (float*)d_out);
}

// Round 7
// 38.570 us; speedup vs baseline: 2.1524x; 2.1524x over previous
//
#include <hip/hip_runtime.h>

#define B_ROWS 32768
#define C_COLS 1000
#define NF4 250                 // C_COLS / 4
#define MAIN_BLOCKS 2048
#define WAVES_TOTAL (MAIN_BLOCKS * 4)
#define HIST_BLOCKS 16
#define BINS_PER_BLOCK 64       // 16 * 64 = 1024 >= 1000

// --- histogram: each of 16 blocks histograms ALL labels in LDS, then
//     writes only its owned 64-bin slice. No global atomics, no zeroing,
//     no memset dispatch needed. ---
__global__ __launch_bounds__(256) void bsl_hist(const int* __restrict__ target,
                                                float* __restrict__ freq) {
    __shared__ unsigned int lh[1024];
    const int tid = threadIdx.x;
    #pragma unroll
    for (int i = tid; i < 1024; i += 256) lh[i] = 0u;
    __syncthreads();
    const int4* t4 = reinterpret_cast<const int4*>(target);
    #pragma unroll 8
    for (int k = 0; k < 32; ++k) {
        int4 v = t4[tid + k * 256];
        atomicAdd(&lh[v.x], 1u);
        atomicAdd(&lh[v.y], 1u);
        atomicAdd(&lh[v.z], 1u);
        atomicAdd(&lh[v.w], 1u);
    }
    __syncthreads();
    if (tid < BINS_PER_BLOCK) {
        const int bin = blockIdx.x * BINS_PER_BLOCK + tid;
        freq[bin] = (float)lh[bin];
    }
}

// --- main: round-2 proven body, verbatim. No fences, no atomics. ---
__global__ __launch_bounds__(256) void bsl_main(const float* __restrict__ pred,
                                                const int* __restrict__ target,
                                                const float* __restrict__ freq,
                                                float* __restrict__ partials) {
    __shared__ float sfreq[C_COLS];
    __shared__ float swave[4];
    const int tid = threadIdx.x;
    const int lane = tid & 63;
    const int wib = tid >> 6;

    for (int i = tid; i < C_COLS; i += 256) sfreq[i] = freq[i];
    __syncthreads();
    const float4* sf4 = reinterpret_cast<const float4*>(sfreq);

    const int gwid = blockIdx.x * 4 + wib;
    float local = 0.0f;

    for (int row = gwid; row < B_ROWS; row += WAVES_TOTAL) {
        const int t = target[row];
        const float4* prow = reinterpret_cast<const float4*>(pred + (size_t)row * C_COLS);
        const int t4i = t >> 2, tm = t & 3;
        float partial = 0.0f, pt = 0.0f;
        #pragma unroll
        for (int k = 0; k < 4; ++k) {
            const int j = k * 64 + lane;
            if (j < NF4) {
                const float4 v = prow[j];
                const float4 f = sf4[j];
                partial += __expf(v.x) * f.x + __expf(v.y) * f.y
                         + __expf(v.z) * f.z + __expf(v.w) * f.w;
                if (j == t4i)
                    pt = (tm & 1) ? ((tm & 2) ? v.w : v.y)
                                  : ((tm & 2) ? v.z : v.x);
            }
        }
        #pragma unroll
        for (int off = 32; off > 0; off >>= 1)
            partial += __shfl_xor(partial, off, 64);
        const float ptb = __shfl(pt, t4i & 63, 64);
        local += logf(partial) - ptb - logf(sfreq[t]);
    }

    if (lane == 0) swave[wib] = local;
    __syncthreads();
    if (tid == 0)
        partials[blockIdx.x] = swave[0] + swave[1] + swave[2] + swave[3];
}

__global__ __launch_bounds__(256) void bsl_finalize(const float* __restrict__ partials,
                                                    float* __restrict__ out) {
    const int tid = threadIdx.x;
    float s = 0.0f;
    for (int i = tid; i < MAIN_BLOCKS; i += 256) s += partials[i];
    #pragma unroll
    for (int off = 32; off > 0; off >>= 1) s += __shfl_xor(s, off, 64);
    __shared__ float sw[4];
    if ((tid & 63) == 0) sw[tid >> 6] = s;
    __syncthreads();
    if (tid == 0) out[0] = (sw[0] + sw[1] + sw[2] + sw[3]) / (float)B_ROWS;
}

extern "C" void kernel_launch(void* const* d_in, const int* in_sizes, int n_in,
                              void* d_out, int out_size, void* d_ws, size_t ws_size,
                              hipStream_t stream) {
    const float* pred = (const float*)d_in[0];
    const int* target = (const int*)d_in[1];

    float* freq     = (float*)d_ws;          // [1024]
    float* partials = freq + 1024;           // [MAIN_BLOCKS]

    bsl_hist<<<HIST_BLOCKS, 256, 0, stream>>>(target, freq);
    bsl_main<<<MAIN_BLOCKS, 256, 0, stream>>>(pred, target, freq, partials);
    bsl_finalize<<<1, 256, 0, stream>>>(partials, (float*)d_out);
}